// Round 12
// baseline (6285.871 us; speedup 1.0000x reference)
//
#include <hip/hip_runtime.h>
#include <math.h>

#define B_ROWS 32768
#define DIM    1024
#define PA 132
#define PB 68

// Numerics contract (verified r10/r11): BLIS sgemm, KC=512. Per C element:
// p1 = serial ascending FMA chain k=0..511, p2 = k=512..1023, C = fl(p1+p2).
// Chunks 0..15 accumulate into acc1 (=p1), 16..31 into acc2 (=p2).

// ---------------- fragments (named members: statically indexed -> registers) ----------------
struct FragT { float4 a0, a1, a2, a3, b0, b1; };
struct FragN { uchar4 a0, a1, a2, a3; float4 b0, b1; };

__device__ __forceinline__ void loadT(const float* pA, const float* pB, FragT& f) {
    f.a0 = *(const float4*)(pA);
    f.a1 = *(const float4*)(pA + 32 * DIM);
    f.a2 = *(const float4*)(pA + 64 * DIM);
    f.a3 = *(const float4*)(pA + 96 * DIM);
    f.b0 = *(const float4*)(pB);
    f.b1 = *(const float4*)(pB + 32 * DIM);
}

// A-tile store with octet-rotation swizzle: element m of k-row c lives at
// col = ((m>>3)+((c>>2)&3) & 15)*8 + (m&7). Write banks: 2-way (free).
__device__ __forceinline__ void storeT(const FragT& f, float (*As)[PA], float (*Bs)[PB],
                                       int kq, int r0) {
    const int c0 = kq * 4, hh = kq & 3;
#pragma unroll
    for (int i = 0; i < 4; ++i) {
        const float4 v = (i == 0) ? f.a0 : (i == 1) ? f.a1 : (i == 2) ? f.a2 : f.a3;
        const int r = r0 + 32 * i;
        const int col = (((r >> 3) + hh) & 15) * 8 + (r & 7);
        As[c0 + 0][col] = v.x; As[c0 + 1][col] = v.y;
        As[c0 + 2][col] = v.z; As[c0 + 3][col] = v.w;
    }
#pragma unroll
    for (int i = 0; i < 2; ++i) {
        const float4 v = (i == 0) ? f.b0 : f.b1;
        const int n = r0 + 32 * i;
        const int col = (((n >> 3) + hh) & 7) * 8 + (n & 7);
        Bs[c0 + 0][col] = v.x; Bs[c0 + 1][col] = v.y;
        Bs[c0 + 2][col] = v.z; Bs[c0 + 3][col] = v.w;
    }
}

__device__ __forceinline__ void computeT(const float (*As)[PA], const float (*Bs)[PB],
                                         int tx, int ty, float (&acc)[8][4]) {
#pragma unroll
    for (int kk = 0; kk < 32; ++kk) {
        const int h = (kk >> 2) & 3;
        const float4 a0 = *(const float4*)&As[kk][((ty + h) & 15) * 8];
        const float4 a1 = *(const float4*)&As[kk][((ty + h) & 15) * 8 + 4];
        const float4 bv = *(const float4*)&Bs[kk][(((tx >> 1) + h) & 7) * 8 + (tx & 1) * 4];
        const float a[8] = {a0.x, a0.y, a0.z, a0.w, a1.x, a1.y, a1.z, a1.w};
        const float b[4] = {bv.x, bv.y, bv.z, bv.w};
#pragma unroll
        for (int i = 0; i < 8; ++i)
#pragma unroll
            for (int j = 0; j < 4; ++j)
                acc[i][j] = fmaf(a[i], b[j], acc[i][j]);
    }
}

// ---------------- K1: y = X @ Pi^T ; argmin -> idxf + idx8 ----------------
__global__ __launch_bounds__(256, 4) void k1_rot_quant(
    const float* __restrict__ X, const float* __restrict__ Pi, const float* __restrict__ C,
    float* __restrict__ idxf, unsigned char* __restrict__ idx8)
{
    __shared__ float As[32][PA];
    __shared__ float Bs[32][PB];
    const int tid = threadIdx.x, tx = tid & 15, ty = tid >> 4;
    const int kq = tid & 7, r0 = tid >> 3;
    const int m0 = blockIdx.y * 128, n0 = blockIdx.x * 64;
    const float* pA = X  + (size_t)(m0 + r0) * DIM + kq * 4;
    const float* pB = Pi + (size_t)(n0 + r0) * DIM + kq * 4;
    float acc1[8][4] = {}, acc2[8][4] = {};
    FragT f;
    loadT(pA, pB, f);
    for (int t = 0; t < 32; ++t) {
        __syncthreads();                       // prev compute done; also drains lgkm
        storeT(f, As, Bs, kq, r0);
        __syncthreads();                       // tile visible; ds_writes drained
        if (t < 31) loadT(pA + (t + 1) * 32, pB + (t + 1) * 32, f);  // hidden under compute
        if (t < 16) computeT(As, Bs, tx, ty, acc1);
        else        computeT(As, Bs, tx, ty, acc2);
    }
    float c8[8];
#pragma unroll
    for (int t = 0; t < 8; ++t) c8[t] = C[t];
#pragma unroll
    for (int i = 0; i < 8; ++i) {
        const size_t o = (size_t)(m0 + ty * 8 + i) * DIM + n0 + tx * 4;
        float fv[4]; unsigned char bv[4];
#pragma unroll
        for (int j = 0; j < 4; ++j) {
            const float y = acc1[i][j] + acc2[i][j];   // fl(p1+p2)
            float best = fabsf(y - c8[0]); int bi = 0;
#pragma unroll
            for (int t2 = 1; t2 < 8; ++t2) {
                const float d = fabsf(y - c8[t2]);
                if (d < best) { best = d; bi = t2; }   // strict <: np first-min tie rule
            }
            fv[j] = (float)bi; bv[j] = (unsigned char)bi;
        }
        *(float4*)&idxf[o] = make_float4(fv[0], fv[1], fv[2], fv[3]);
        *(uchar4*)&idx8[o] = make_uchar4(bv[0], bv[1], bv[2], bv[3]);
    }
}

// ---------------- K3: xhat = yhat @ Pi ; R = X - xhat ; fused row-norm partials ----------------
__device__ __forceinline__ void storeN(const FragN& f, const float* clut,
                                       float (*As)[PA], float (*Bs)[PB],
                                       int kq, int r0, int nq, int kr0) {
    const int c0 = kq * 4, hh = kq & 3;
#pragma unroll
    for (int i = 0; i < 4; ++i) {
        const uchar4 v = (i == 0) ? f.a0 : (i == 1) ? f.a1 : (i == 2) ? f.a2 : f.a3;
        const int r = r0 + 32 * i;
        const int col = (((r >> 3) + hh) & 15) * 8 + (r & 7);
        As[c0 + 0][col] = clut[v.x]; As[c0 + 1][col] = clut[v.y];
        As[c0 + 2][col] = clut[v.z]; As[c0 + 3][col] = clut[v.w];
    }
    *(float4*)&Bs[kr0][nq * 4]      = f.b0;
    *(float4*)&Bs[kr0 + 16][nq * 4] = f.b1;
}

__global__ __launch_bounds__(256, 4) void k3_unrot_residual(
    const float* __restrict__ X, const float* __restrict__ Pi, const float* __restrict__ C,
    const unsigned char* __restrict__ idx8, float* __restrict__ R, double* __restrict__ nrm2)
{
    __shared__ float As[32][PA];
    __shared__ float Bs[32][PB];
    __shared__ float clut[8];
    const int tid = threadIdx.x, tx = tid & 15, ty = tid >> 4;
    const int kq = tid & 7, r0 = tid >> 3;
    const int nq = tid & 15, kr0 = tid >> 4;
    const int m0 = blockIdx.y * 128, n0 = blockIdx.x * 64;
    if (tid < 8) clut[tid] = C[tid];
    const unsigned char* pA = idx8 + (size_t)(m0 + r0) * DIM + kq * 4;
    const float*         pB = Pi + (size_t)kr0 * DIM + n0 + nq * 4;
    float acc1[8][4] = {}, acc2[8][4] = {};
    FragN f;
    f.a0 = *(const uchar4*)(pA);
    f.a1 = *(const uchar4*)(pA + 32 * DIM);
    f.a2 = *(const uchar4*)(pA + 64 * DIM);
    f.a3 = *(const uchar4*)(pA + 96 * DIM);
    f.b0 = *(const float4*)(pB);
    f.b1 = *(const float4*)(pB + 16 * DIM);
    for (int t = 0; t < 32; ++t) {
        __syncthreads();
        storeN(f, clut, As, Bs, kq, r0, nq, kr0);
        __syncthreads();
        if (t < 31) {
            const unsigned char* qA = pA + (t + 1) * 32;
            const float* qB = pB + (size_t)(t + 1) * 32 * DIM;
            f.a0 = *(const uchar4*)(qA);
            f.a1 = *(const uchar4*)(qA + 32 * DIM);
            f.a2 = *(const uchar4*)(qA + 64 * DIM);
            f.a3 = *(const uchar4*)(qA + 96 * DIM);
            f.b0 = *(const float4*)(qB);
            f.b1 = *(const float4*)(qB + 16 * DIM);
        }
        // compute: A swizzled read, B linear read
#pragma unroll
        for (int kk = 0; kk < 32; ++kk) {
            const int h = (kk >> 2) & 3;
            const float4 a0 = *(const float4*)&As[kk][((ty + h) & 15) * 8];
            const float4 a1 = *(const float4*)&As[kk][((ty + h) & 15) * 8 + 4];
            const float4 bv = *(const float4*)&Bs[kk][tx * 4];
            const float a[8] = {a0.x, a0.y, a0.z, a0.w, a1.x, a1.y, a1.z, a1.w};
            const float b[4] = {bv.x, bv.y, bv.z, bv.w};
            if (t < 16) {
#pragma unroll
                for (int i = 0; i < 8; ++i)
#pragma unroll
                    for (int j = 0; j < 4; ++j) acc1[i][j] = fmaf(a[i], b[j], acc1[i][j]);
            } else {
#pragma unroll
                for (int i = 0; i < 8; ++i)
#pragma unroll
                    for (int j = 0; j < 4; ++j) acc2[i][j] = fmaf(a[i], b[j], acc2[i][j]);
            }
        }
    }
#pragma unroll
    for (int i = 0; i < 8; ++i) {
        const int row = m0 + ty * 8 + i;
        const size_t o = (size_t)row * DIM + n0 + tx * 4;
        const float4 xv = *(const float4*)&X[o];
        const float r0v = xv.x - (acc1[i][0] + acc2[i][0]);
        const float r1v = xv.y - (acc1[i][1] + acc2[i][1]);
        const float r2v = xv.z - (acc1[i][2] + acc2[i][2]);
        const float r3v = xv.w - (acc1[i][3] + acc2[i][3]);
        *(float4*)&R[o] = make_float4(r0v, r1v, r2v, r3v);
        double s = (double)r0v * r0v;
        s = fma((double)r1v, (double)r1v, s);
        s = fma((double)r2v, (double)r2v, s);
        s = fma((double)r3v, (double)r3v, s);
#pragma unroll
        for (int mask = 1; mask < 16; mask <<= 1) s += __shfl_xor(s, mask, 16);
        if (tx == 0) atomicAdd(&nrm2[row], s);
    }
}

// ---------------- K5: P = R @ S^T ; sign ----------------
__global__ __launch_bounds__(256, 4) void k5_qjl(
    const float* __restrict__ R, const float* __restrict__ S, float* __restrict__ sgn)
{
    __shared__ float As[32][PA];
    __shared__ float Bs[32][PB];
    const int tid = threadIdx.x, tx = tid & 15, ty = tid >> 4;
    const int kq = tid & 7, r0 = tid >> 3;
    const int m0 = blockIdx.y * 128, n0 = blockIdx.x * 64;
    const float* pA = R + (size_t)(m0 + r0) * DIM + kq * 4;
    const float* pB = S + (size_t)(n0 + r0) * DIM + kq * 4;
    float acc1[8][4] = {}, acc2[8][4] = {};
    FragT f;
    loadT(pA, pB, f);
    for (int t = 0; t < 32; ++t) {
        __syncthreads();
        storeT(f, As, Bs, kq, r0);
        __syncthreads();
        if (t < 31) loadT(pA + (t + 1) * 32, pB + (t + 1) * 32, f);
        if (t < 16) computeT(As, Bs, tx, ty, acc1);
        else        computeT(As, Bs, tx, ty, acc2);
    }
#pragma unroll
    for (int i = 0; i < 8; ++i) {
        const size_t o = (size_t)(m0 + ty * 8 + i) * DIM + n0 + tx * 4;
        const float p0 = acc1[i][0] + acc2[i][0], p1 = acc1[i][1] + acc2[i][1];
        const float p2 = acc1[i][2] + acc2[i][2], p3 = acc1[i][3] + acc2[i][3];
        *(float4*)&sgn[o] = make_float4((p0 >= 0.f) ? 1.f : -1.f, (p1 >= 0.f) ? 1.f : -1.f,
                                        (p2 >= 0.f) ? 1.f : -1.f, (p3 >= 0.f) ? 1.f : -1.f);
    }
}

// ---------------- KN: norms = sqrt(nrm2) ----------------
__global__ __launch_bounds__(256) void kN_sqrt(const double* __restrict__ nrm2, float* __restrict__ nrm)
{
    const int i = blockIdx.x * 256 + threadIdx.x;
    if (i < B_ROWS) nrm[i] = (float)sqrt(nrm2[i]);
}

extern "C" void kernel_launch(void* const* d_in, const int* in_sizes, int n_in,
                              void* d_out, int out_size, void* d_ws, size_t ws_size,
                              hipStream_t stream) {
    const float* X  = (const float*)d_in[0];
    const float* Pi = (const float*)d_in[1];
    const float* C  = (const float*)d_in[2];
    const float* S  = (const float*)d_in[3];

    float* out  = (float*)d_out;
    float* idxf = out;                                   // B*D (index values)
    float* sgn  = out + (size_t)B_ROWS * DIM;            // B*D (+-1)
    float* nrm  = sgn + (size_t)B_ROWS * DIM;            // B

    char* ws = (char*)d_ws;
    float*         R    = (float*)ws;                                          // 128 MiB
    unsigned char* idx8 = (unsigned char*)(ws + (size_t)B_ROWS * DIM * 4);     //  32 MiB
    double*        nrm2 = (double*)(ws + (size_t)B_ROWS * DIM * 5);            // 256 KiB

    hipMemsetAsync(nrm2, 0, (size_t)B_ROWS * sizeof(double), stream);

    dim3 blk(256);
    dim3 gG(DIM / 64, B_ROWS / 128);                     // 16 x 256 = 4096 blocks

    k1_rot_quant     <<<gG, blk, 0, stream>>>(X, Pi, C, idxf, idx8);
    k3_unrot_residual<<<gG, blk, 0, stream>>>(X, Pi, C, idx8, R, nrm2);
    kN_sqrt          <<<dim3(B_ROWS / 256), blk, 0, stream>>>(nrm2, nrm);
    k5_qjl           <<<gG, blk, 0, stream>>>(R, S, sgn);
}

// Round 13
// 3514.701 us; speedup vs baseline: 1.7885x; 1.7885x over previous
//
#include <hip/hip_runtime.h>
#include <math.h>

#define B_ROWS 32768
#define DIM    1024
#define PA 132
#define PB 68

// Numerics contract (verified r10/r11): BLIS sgemm, KC=512. Per C element:
// p1 = serial ascending FMA chain k=0..511, p2 = k=512..1023, C = fl(p1+p2).
// Chunks 0..15 accumulate into acc1 (=p1), 16..31 into acc2 (=p2).
//
// r12 lesson: NO min-occupancy launch_bounds here — accumulator footprint is
// ~64 VGPRs; (256,4) capped VGPRs at 64 and spilled acc to scratch (12.6 GB
// HBM traffic, 2.3x slowdown). Plain __launch_bounds__(256) -> ~110 VGPR.

// ---------------- fragments (named members: statically indexed -> registers) ----------------
struct FragT { float4 a0, a1, a2, a3, b0, b1; };
struct FragN { uchar4 a0, a1, a2, a3; float4 b0, b1; };

__device__ __forceinline__ void loadT(const float* pA, const float* pB, FragT& f) {
    f.a0 = *(const float4*)(pA);
    f.a1 = *(const float4*)(pA + 32 * DIM);
    f.a2 = *(const float4*)(pA + 64 * DIM);
    f.a3 = *(const float4*)(pA + 96 * DIM);
    f.b0 = *(const float4*)(pB);
    f.b1 = *(const float4*)(pB + 32 * DIM);
}

// A-tile store with octet-rotation swizzle: element m of k-row c lives at
// col = ((m>>3)+((c>>2)&3) & 15)*8 + (m&7). Write banks: 2-way (free).
__device__ __forceinline__ void storeT(const FragT& f, float (*As)[PA], float (*Bs)[PB],
                                       int kq, int r0) {
    const int c0 = kq * 4, hh = kq & 3;
#pragma unroll
    for (int i = 0; i < 4; ++i) {
        const float4 v = (i == 0) ? f.a0 : (i == 1) ? f.a1 : (i == 2) ? f.a2 : f.a3;
        const int r = r0 + 32 * i;
        const int col = (((r >> 3) + hh) & 15) * 8 + (r & 7);
        As[c0 + 0][col] = v.x; As[c0 + 1][col] = v.y;
        As[c0 + 2][col] = v.z; As[c0 + 3][col] = v.w;
    }
#pragma unroll
    for (int i = 0; i < 2; ++i) {
        const float4 v = (i == 0) ? f.b0 : f.b1;
        const int n = r0 + 32 * i;
        const int col = (((n >> 3) + hh) & 7) * 8 + (n & 7);
        Bs[c0 + 0][col] = v.x; Bs[c0 + 1][col] = v.y;
        Bs[c0 + 2][col] = v.z; Bs[c0 + 3][col] = v.w;
    }
}

__device__ __forceinline__ void computeT(const float (*As)[PA], const float (*Bs)[PB],
                                         int tx, int ty, float (&acc)[8][4]) {
#pragma unroll
    for (int kk = 0; kk < 32; ++kk) {
        const int h = (kk >> 2) & 3;
        const float4 a0 = *(const float4*)&As[kk][((ty + h) & 15) * 8];
        const float4 a1 = *(const float4*)&As[kk][((ty + h) & 15) * 8 + 4];
        const float4 bv = *(const float4*)&Bs[kk][(((tx >> 1) + h) & 7) * 8 + (tx & 1) * 4];
        const float a[8] = {a0.x, a0.y, a0.z, a0.w, a1.x, a1.y, a1.z, a1.w};
        const float b[4] = {bv.x, bv.y, bv.z, bv.w};
#pragma unroll
        for (int i = 0; i < 8; ++i)
#pragma unroll
            for (int j = 0; j < 4; ++j)
                acc[i][j] = fmaf(a[i], b[j], acc[i][j]);
    }
}

// ---------------- K1: y = X @ Pi^T ; argmin -> idxf + idx8 ----------------
__global__ __launch_bounds__(256) void k1_rot_quant(
    const float* __restrict__ X, const float* __restrict__ Pi, const float* __restrict__ C,
    float* __restrict__ idxf, unsigned char* __restrict__ idx8)
{
    __shared__ float As[32][PA];
    __shared__ float Bs[32][PB];
    const int tid = threadIdx.x, tx = tid & 15, ty = tid >> 4;
    const int kq = tid & 7, r0 = tid >> 3;
    const int m0 = blockIdx.y * 128, n0 = blockIdx.x * 64;
    const float* pA = X  + (size_t)(m0 + r0) * DIM + kq * 4;
    const float* pB = Pi + (size_t)(n0 + r0) * DIM + kq * 4;
    float acc1[8][4] = {}, acc2[8][4] = {};
    FragT f;
    loadT(pA, pB, f);
    for (int t = 0; t < 32; ++t) {
        __syncthreads();                       // prev compute done
        storeT(f, As, Bs, kq, r0);
        __syncthreads();                       // tile visible
        if (t < 31) loadT(pA + (t + 1) * 32, pB + (t + 1) * 32, f);  // hidden under compute
        if (t < 16) computeT(As, Bs, tx, ty, acc1);
        else        computeT(As, Bs, tx, ty, acc2);
    }
    float c8[8];
#pragma unroll
    for (int t = 0; t < 8; ++t) c8[t] = C[t];
#pragma unroll
    for (int i = 0; i < 8; ++i) {
        const size_t o = (size_t)(m0 + ty * 8 + i) * DIM + n0 + tx * 4;
        float fv[4]; unsigned char bv[4];
#pragma unroll
        for (int j = 0; j < 4; ++j) {
            const float y = acc1[i][j] + acc2[i][j];   // fl(p1+p2)
            float best = fabsf(y - c8[0]); int bi = 0;
#pragma unroll
            for (int t2 = 1; t2 < 8; ++t2) {
                const float d = fabsf(y - c8[t2]);
                if (d < best) { best = d; bi = t2; }   // strict <: np first-min tie rule
            }
            fv[j] = (float)bi; bv[j] = (unsigned char)bi;
        }
        *(float4*)&idxf[o] = make_float4(fv[0], fv[1], fv[2], fv[3]);
        *(uchar4*)&idx8[o] = make_uchar4(bv[0], bv[1], bv[2], bv[3]);
    }
}

// ---------------- K3: xhat = yhat @ Pi ; R = X - xhat ; fused row-norm partials ----------------
__device__ __forceinline__ void storeN(const FragN& f, const float* clut,
                                       float (*As)[PA], float (*Bs)[PB],
                                       int kq, int r0, int nq, int kr0) {
    const int c0 = kq * 4, hh = kq & 3;
#pragma unroll
    for (int i = 0; i < 4; ++i) {
        const uchar4 v = (i == 0) ? f.a0 : (i == 1) ? f.a1 : (i == 2) ? f.a2 : f.a3;
        const int r = r0 + 32 * i;
        const int col = (((r >> 3) + hh) & 15) * 8 + (r & 7);
        As[c0 + 0][col] = clut[v.x]; As[c0 + 1][col] = clut[v.y];
        As[c0 + 2][col] = clut[v.z]; As[c0 + 3][col] = clut[v.w];
    }
    *(float4*)&Bs[kr0][nq * 4]      = f.b0;
    *(float4*)&Bs[kr0 + 16][nq * 4] = f.b1;
}

__global__ __launch_bounds__(256) void k3_unrot_residual(
    const float* __restrict__ X, const float* __restrict__ Pi, const float* __restrict__ C,
    const unsigned char* __restrict__ idx8, float* __restrict__ R, double* __restrict__ nrm2)
{
    __shared__ float As[32][PA];
    __shared__ float Bs[32][PB];
    __shared__ float clut[8];
    const int tid = threadIdx.x, tx = tid & 15, ty = tid >> 4;
    const int kq = tid & 7, r0 = tid >> 3;
    const int nq = tid & 15, kr0 = tid >> 4;
    const int m0 = blockIdx.y * 128, n0 = blockIdx.x * 64;
    if (tid < 8) clut[tid] = C[tid];
    const unsigned char* pA = idx8 + (size_t)(m0 + r0) * DIM + kq * 4;
    const float*         pB = Pi + (size_t)kr0 * DIM + n0 + nq * 4;
    float acc1[8][4] = {}, acc2[8][4] = {};
    FragN f;
    f.a0 = *(const uchar4*)(pA);
    f.a1 = *(const uchar4*)(pA + 32 * DIM);
    f.a2 = *(const uchar4*)(pA + 64 * DIM);
    f.a3 = *(const uchar4*)(pA + 96 * DIM);
    f.b0 = *(const float4*)(pB);
    f.b1 = *(const float4*)(pB + 16 * DIM);
    for (int t = 0; t < 32; ++t) {
        __syncthreads();
        storeN(f, clut, As, Bs, kq, r0, nq, kr0);
        __syncthreads();
        if (t < 31) {
            const unsigned char* qA = pA + (t + 1) * 32;
            const float* qB = pB + (size_t)(t + 1) * 32 * DIM;
            f.a0 = *(const uchar4*)(qA);
            f.a1 = *(const uchar4*)(qA + 32 * DIM);
            f.a2 = *(const uchar4*)(qA + 64 * DIM);
            f.a3 = *(const uchar4*)(qA + 96 * DIM);
            f.b0 = *(const float4*)(qB);
            f.b1 = *(const float4*)(qB + 16 * DIM);
        }
#pragma unroll
        for (int kk = 0; kk < 32; ++kk) {
            const int h = (kk >> 2) & 3;
            const float4 a0 = *(const float4*)&As[kk][((ty + h) & 15) * 8];
            const float4 a1 = *(const float4*)&As[kk][((ty + h) & 15) * 8 + 4];
            const float4 bv = *(const float4*)&Bs[kk][tx * 4];
            const float a[8] = {a0.x, a0.y, a0.z, a0.w, a1.x, a1.y, a1.z, a1.w};
            const float b[4] = {bv.x, bv.y, bv.z, bv.w};
            if (t < 16) {
#pragma unroll
                for (int i = 0; i < 8; ++i)
#pragma unroll
                    for (int j = 0; j < 4; ++j) acc1[i][j] = fmaf(a[i], b[j], acc1[i][j]);
            } else {
#pragma unroll
                for (int i = 0; i < 8; ++i)
#pragma unroll
                    for (int j = 0; j < 4; ++j) acc2[i][j] = fmaf(a[i], b[j], acc2[i][j]);
            }
        }
    }
#pragma unroll
    for (int i = 0; i < 8; ++i) {
        const int row = m0 + ty * 8 + i;
        const size_t o = (size_t)row * DIM + n0 + tx * 4;
        const float4 xv = *(const float4*)&X[o];
        const float r0v = xv.x - (acc1[i][0] + acc2[i][0]);
        const float r1v = xv.y - (acc1[i][1] + acc2[i][1]);
        const float r2v = xv.z - (acc1[i][2] + acc2[i][2]);
        const float r3v = xv.w - (acc1[i][3] + acc2[i][3]);
        *(float4*)&R[o] = make_float4(r0v, r1v, r2v, r3v);
        double s = (double)r0v * r0v;
        s = fma((double)r1v, (double)r1v, s);
        s = fma((double)r2v, (double)r2v, s);
        s = fma((double)r3v, (double)r3v, s);
#pragma unroll
        for (int mask = 1; mask < 16; mask <<= 1) s += __shfl_xor(s, mask, 16);
        if (tx == 0) atomicAdd(&nrm2[row], s);
    }
}

// ---------------- K5: P = R @ S^T ; sign ----------------
__global__ __launch_bounds__(256) void k5_qjl(
    const float* __restrict__ R, const float* __restrict__ S, float* __restrict__ sgn)
{
    __shared__ float As[32][PA];
    __shared__ float Bs[32][PB];
    const int tid = threadIdx.x, tx = tid & 15, ty = tid >> 4;
    const int kq = tid & 7, r0 = tid >> 3;
    const int m0 = blockIdx.y * 128, n0 = blockIdx.x * 64;
    const float* pA = R + (size_t)(m0 + r0) * DIM + kq * 4;
    const float* pB = S + (size_t)(n0 + r0) * DIM + kq * 4;
    float acc1[8][4] = {}, acc2[8][4] = {};
    FragT f;
    loadT(pA, pB, f);
    for (int t = 0; t < 32; ++t) {
        __syncthreads();
        storeT(f, As, Bs, kq, r0);
        __syncthreads();
        if (t < 31) loadT(pA + (t + 1) * 32, pB + (t + 1) * 32, f);
        if (t < 16) computeT(As, Bs, tx, ty, acc1);
        else        computeT(As, Bs, tx, ty, acc2);
    }
#pragma unroll
    for (int i = 0; i < 8; ++i) {
        const size_t o = (size_t)(m0 + ty * 8 + i) * DIM + n0 + tx * 4;
        const float p0 = acc1[i][0] + acc2[i][0], p1 = acc1[i][1] + acc2[i][1];
        const float p2 = acc1[i][2] + acc2[i][2], p3 = acc1[i][3] + acc2[i][3];
        *(float4*)&sgn[o] = make_float4((p0 >= 0.f) ? 1.f : -1.f, (p1 >= 0.f) ? 1.f : -1.f,
                                        (p2 >= 0.f) ? 1.f : -1.f, (p3 >= 0.f) ? 1.f : -1.f);
    }
}

// ---------------- KN: norms = sqrt(nrm2) ----------------
__global__ __launch_bounds__(256) void kN_sqrt(const double* __restrict__ nrm2, float* __restrict__ nrm)
{
    const int i = blockIdx.x * 256 + threadIdx.x;
    if (i < B_ROWS) nrm[i] = (float)sqrt(nrm2[i]);
}

extern "C" void kernel_launch(void* const* d_in, const int* in_sizes, int n_in,
                              void* d_out, int out_size, void* d_ws, size_t ws_size,
                              hipStream_t stream) {
    const float* X  = (const float*)d_in[0];
    const float* Pi = (const float*)d_in[1];
    const float* C  = (const float*)d_in[2];
    const float* S  = (const float*)d_in[3];

    float* out  = (float*)d_out;
    float* idxf = out;                                   // B*D (index values)
    float* sgn  = out + (size_t)B_ROWS * DIM;            // B*D (+-1)
    float* nrm  = sgn + (size_t)B_ROWS * DIM;            // B

    char* ws = (char*)d_ws;
    float*         R    = (float*)ws;                                          // 128 MiB
    unsigned char* idx8 = (unsigned char*)(ws + (size_t)B_ROWS * DIM * 4);     //  32 MiB
    double*        nrm2 = (double*)(ws + (size_t)B_ROWS * DIM * 5);            // 256 KiB

    hipMemsetAsync(nrm2, 0, (size_t)B_ROWS * sizeof(double), stream);

    dim3 blk(256);
    dim3 gG(DIM / 64, B_ROWS / 128);                     // 16 x 256 = 4096 blocks

    k1_rot_quant     <<<gG, blk, 0, stream>>>(X, Pi, C, idxf, idx8);
    k3_unrot_residual<<<gG, blk, 0, stream>>>(X, Pi, C, idx8, R, nrm2);
    kN_sqrt          <<<dim3(B_ROWS / 256), blk, 0, stream>>>(nrm2, nrm);
    k5_qjl           <<<gG, blk, 0, stream>>>(R, S, sgn);
}